// Round 16
// baseline (149.589 us; speedup 1.0000x reference)
//
#include <hip/hip_runtime.h>
#include <hip/hip_bf16.h>
#include <stdint.h>

#define NPTS 2048
#define DM 256
#define NH 4
#define DH 64
#define KK 1024

// ws layout (ushort units):
//  Qh bf16 [4][2048][64] @ 0
//  Ql bf16               @ 1*524288
//  Kh bf16               @ 2*524288
//  Kl bf16               @ 3*524288
//  Vt bf16 [4][64][2048] @ 4*524288   (transposed: channel-major)
#define QH_OFF 0
#define QL_OFF (NH*NPTS*DH)
#define KH_OFF (2*NH*NPTS*DH)
#define KL_OFF (3*NH*NPTS*DH)
#define VT_OFF (4*NH*NPTS*DH)

typedef __attribute__((ext_vector_type(8)))  short bf16x8;
typedef __attribute__((ext_vector_type(4)))  float f32x4;
typedef __attribute__((ext_vector_type(4)))  uint  u32x4;

__device__ inline ushort bf16rn(float f) {
    uint32_t u = __float_as_uint(f);
    uint32_t r = (u + 0x7FFFu + ((u >> 16) & 1u)) >> 16;
    return (ushort)r;
}
__device__ inline float bf16tof(ushort h) {
    return __uint_as_float(((uint32_t)h) << 16);
}
__device__ inline uint32_t f2u(float f) {
    uint32_t x = __float_as_uint(f);
    return (x & 0x80000000u) ? ~x : (x | 0x80000000u);
}
__device__ inline float u2f(uint32_t u) {
    uint32_t x = (u & 0x80000000u) ? (u ^ 0x80000000u) : ~u;
    return __uint_as_float(x);
}

// ---------------- Kernel 1: projections + rotary + bf16 hi/lo split + V^T ----------------
__global__ __launch_bounds__(256) void proj_rope_kernel(
    const float* __restrict__ xq, const float* __restrict__ xk, const float* __restrict__ xv,
    const float* __restrict__ emb,
    const float* __restrict__ Wq, const float* __restrict__ bq,
    const float* __restrict__ Wk, const float* __restrict__ bk,
    const float* __restrict__ Wv, const float* __restrict__ bv,
    ushort* __restrict__ wsu)
{
    const int z = blockIdx.y;
    const int n0 = blockIdx.x * 8;
    const float* X = (z==0) ? xq : (z==1) ? xk : xv;
    const float* W = (z==0) ? Wq : (z==1) ? Wk : Wv;
    const float* B = (z==0) ? bq : (z==1) ? bk : bv;

    __shared__ float s_in[8][DM];
    {
        const float4* X4 = (const float4*)(X + (size_t)n0 * DM);
        float4* s4 = (float4*)&s_in[0][0];
        #pragma unroll
        for (int i = 0; i < 2; i++) {
            int f = threadIdx.x + 256*i;
            s4[f] = X4[f];
        }
    }
    __syncthreads();

    const int c = threadIdx.x;
    const int h = c >> 6, d = c & 63;
    const float bias = B[c];
    float acc[8];
    #pragma unroll
    for (int r = 0; r < 8; r++) acc[r] = bias;

    const float4* W4 = (const float4*)(W + (size_t)c * DM);
    #pragma unroll 4
    for (int k4 = 0; k4 < DM/4; k4++) {
        float4 w = W4[k4];
        #pragma unroll
        for (int r = 0; r < 8; r++) {
            float4 sv = *(const float4*)&s_in[r][k4*4];
            acc[r] = fmaf(sv.x, w.x, acc[r]);
            acc[r] = fmaf(sv.y, w.y, acc[r]);
            acc[r] = fmaf(sv.z, w.z, acc[r]);
            acc[r] = fmaf(sv.w, w.w, acc[r]);
        }
    }

    if (z < 2) {
        const int p = d >> 1;
        #pragma unroll
        for (int r = 0; r < 8; r++) {
            float th = emb[(size_t)(n0 + r)*(DM/2) + h*32 + p];
            float sn, cs;
            __sincosf(th, &sn, &cs);
            float partner = __shfl_xor(acc[r], 1);
            acc[r] = (d & 1) ? (acc[r]*cs + partner*sn) : (acc[r]*cs - partner*sn);
            if (z == 0) acc[r] *= 0.125f;   // 1/sqrt(64) folded into Q
        }
        ushort* hi = wsu + ((z==0) ? QH_OFF : KH_OFF);
        ushort* lo = wsu + ((z==0) ? QL_OFF : KL_OFF);
        #pragma unroll
        for (int r = 0; r < 8; r++) {
            size_t idx = ((size_t)(h*NPTS + n0 + r))*DH + d;
            ushort hb = bf16rn(acc[r]);
            float res = acc[r] - bf16tof(hb);
            hi[idx] = hb;
            lo[idx] = bf16rn(res);
        }
    } else {
        __syncthreads();
        #pragma unroll
        for (int r = 0; r < 8; r++) s_in[r][c] = acc[r];
        __syncthreads();
        ushort tmp[8];
        #pragma unroll
        for (int r = 0; r < 8; r++) tmp[r] = bf16rn(s_in[r][c]);
        *(bf16x8*)(wsu + VT_OFF + (size_t)c*NPTS + n0) = *(bf16x8*)tmp;
    }
}

// ---------------- Kernel 2: fused scores + top-k + softmax + probs + PV ----------------
// grid (1024), block 512 (8 waves) = 8 query rows of one head, ONE row per wave.
// LDS 64 KB = S[8 rows][2048 cols] f32 (single-pass staging; row region = 8 KB).
// ZERO score keys in registers: search/softmax re-read keys from LDS each iteration.
// -> honest VGPR ~40, no spill; 2 independent blocks/CU (separate barrier domains).
// Overlays: P bf16 [row][2048] at row bytes [0,4096) (ascending-chunk in-place);
//           PV partials [wave][8 rows][64 d] at row-region bytes [4096,6144).
// Only 3 barriers.
__global__ __launch_bounds__(512, 4) void fused_attn_kernel(const ushort* __restrict__ wsu,
                                                            float* __restrict__ out)
{
    const int id = blockIdx.x;
    const int c8 = id & 7;                      // XCD (round-robin heuristic)
    const int h  = c8 >> 1;                     // one head per XCD pair
    const int n0 = 8 * ((id >> 3) + 128 * (c8 & 1));
    float* sp = out + (size_t)NPTS*DM;
    __shared__ float LB[16384];                 // 65536 B
    char* lds = (char*)LB;

    const int w  = threadIdx.x >> 6, l = threadIdx.x & 63;
    const int cl = l & 15, cg = l >> 4;
    const int qrow = cl & 7;                    // Q row (duplicated into B cols 8-15)
    char* myrow = lds + (size_t)w*8192u;        // this wave's score row region

    // ========== phase A: single-pass staging; wave w covers cols [256w, 256w+256) ==========
    {
        const size_t qbase = ((size_t)(h*NPTS + n0 + qrow))*DH + 8*cg;
        bf16x8 qh0 = *(const bf16x8*)(wsu + QH_OFF + qbase);
        bf16x8 qh1 = *(const bf16x8*)(wsu + QH_OFF + qbase + 32);

        const int col0 = 256*w;
        #pragma unroll 2
        for (int t = 0; t < 16; t++) {
            const size_t kb = ((size_t)(h*NPTS + col0 + 16*t + cl))*DH + 8*cg;
            f32x4 a = {0.f, 0.f, 0.f, 0.f};
            bf16x8 ah0 = *(const bf16x8*)(wsu + KH_OFF + kb);
            a = __builtin_amdgcn_mfma_f32_16x16x32_bf16(ah0, qh0, a, 0, 0, 0);
            {
                bf16x8 al0 = *(const bf16x8*)(wsu + KL_OFF + kb);
                a = __builtin_amdgcn_mfma_f32_16x16x32_bf16(al0, qh0, a, 0, 0, 0);
            }
            {
                bf16x8 ql0 = *(const bf16x8*)(wsu + QL_OFF + qbase);
                a = __builtin_amdgcn_mfma_f32_16x16x32_bf16(ah0, ql0, a, 0, 0, 0);
            }
            bf16x8 ah1 = *(const bf16x8*)(wsu + KH_OFF + kb + 32);
            a = __builtin_amdgcn_mfma_f32_16x16x32_bf16(ah1, qh1, a, 0, 0, 0);
            {
                bf16x8 al1 = *(const bf16x8*)(wsu + KL_OFF + kb + 32);
                a = __builtin_amdgcn_mfma_f32_16x16x32_bf16(al1, qh1, a, 0, 0, 0);
            }
            {
                bf16x8 ql1 = *(const bf16x8*)(wsu + QL_OFF + qbase + 32);
                a = __builtin_amdgcn_mfma_f32_16x16x32_bf16(ah1, ql1, a, 0, 0, 0);
            }
            // C: q-row = qrow (cl<8 valid), col = 256w + 16t + 4cg + reg
            if (cl < 8) {
                uint32_t byte = (uint32_t)qrow*8192u + 1024u*(uint32_t)w
                              + 64u*(uint32_t)t + 16u*(uint32_t)cg;
                *(f32x4*)(lds + byte) = a;
            }
        }
    }
    __syncthreads();                            // (1) all scores staged

    // ========== phase B: wave-local on own row (no barriers) ==========
    // convert f32 scores -> monotone uint keys in place; fold max AND min
    uint32_t mu = 0u, mn = 0xFFFFFFFFu;
    #pragma unroll
    for (int j = 0; j < 8; j++) {
        uint32_t off = 16u*(uint32_t)(l + 64*j);
        f32x4 v = *(const f32x4*)(myrow + off);
        u32x4 kv;
        #pragma unroll
        for (int i = 0; i < 4; i++) {
            kv[i] = f2u(v[i]);
            mu = (kv[i] > mu) ? kv[i] : mu;
            mn = (kv[i] < mn) ? kv[i] : mn;
        }
        *(u32x4*)(myrow + off) = kv;
    }
    #pragma unroll
    for (int off = 32; off; off >>= 1) {
        uint32_t o = (uint32_t)__shfl_xor((int)mu, off);
        mu = (o > mu) ? o : mu;
        uint32_t o2 = (uint32_t)__shfl_xor((int)mn, off);
        mn = (o2 < mn) ? o2 : mn;
    }
    const float mx = u2f(mu);

    // 1-bit binary search (keys in LDS), from first min/max differing bit, early exit
    uint32_t cur = 0u;
    {
        uint32_t diff = mu ^ mn;
        int hb = (diff != 0u) ? (31 - __builtin_clz(diff)) : -1;
        if (hb >= 0) {
            cur = (hb < 31) ? (mu & ~((2u << hb) - 1u)) : 0u;  // common prefix above hb
            for (int bit = hb; bit >= 0; bit--) {
                uint32_t cand = cur | (1u << bit);
                int c = 0;
                #pragma unroll
                for (int j = 0; j < 8; j++) {
                    u32x4 kv = *(const u32x4*)(myrow + 16u*(uint32_t)(l + 64*j));
                    #pragma unroll
                    for (int i = 0; i < 4; i++) c += (int)__popcll(__ballot(kv[i] >= cand));
                }
                if (c >= KK) { cur = cand; if (c == KK) break; }
            }
        }
    }

    // zsum (keys from LDS)
    float zsum = 0.f;
    #pragma unroll
    for (int j = 0; j < 8; j++) {
        u32x4 kv = *(const u32x4*)(myrow + 16u*(uint32_t)(l + 64*j));
        #pragma unroll
        for (int i = 0; i < 4; i++)
            if (kv[i] >= cur) zsum += __expf(u2f(kv[i]) - mx);
    }
    #pragma unroll
    for (int off = 32; off; off >>= 1) zsum += __shfl_xor(zsum, off);
    const float rz = 1.f / zsum;

    // P overlay in place, ascending chunks of 256 cols.
    // key col c at byte 4c; P col c at byte 2c. Write of chunk i ([512i,512i+512))
    // clobbers only chunk i/2 keys: i=1 clobbers chunk 0 (held in regs), i>=2 clobbers
    // already-consumed chunks. Global prob stores (plain, ACK at L2) interleaved.
    f32x4* grow4 = (f32x4*)(sp + ((size_t)(h*NPTS + n0 + w))*NPTS);
    u32x4 kv0 = *(const u32x4*)(myrow + 16u*(uint32_t)l);   // chunk 0: cols 4l..4l+3
    #pragma unroll
    for (int i = 1; i < 8; i++) {
        u32x4 kv = *(const u32x4*)(myrow + 16u*(uint32_t)(64*i + l));
        f32x4 p;
        #pragma unroll
        for (int q = 0; q < 4; q++)
            p[q] = (kv[q] >= cur) ? __expf(u2f(kv[q]) - mx) * rz : 0.f;
        uint32_t pk0 = ((uint32_t)bf16rn(p[1]) << 16) | (uint32_t)bf16rn(p[0]);
        uint32_t pk1 = ((uint32_t)bf16rn(p[3]) << 16) | (uint32_t)bf16rn(p[2]);
        *(uint2*)(myrow + 512u*(uint32_t)i + 8u*(uint32_t)l) = make_uint2(pk0, pk1);
        grow4[64*i + l] = p;
    }
    {
        f32x4 p;
        #pragma unroll
        for (int q = 0; q < 4; q++)
            p[q] = (kv0[q] >= cur) ? __expf(u2f(kv0[q]) - mx) * rz : 0.f;
        uint32_t pk0 = ((uint32_t)bf16rn(p[1]) << 16) | (uint32_t)bf16rn(p[0]);
        uint32_t pk1 = ((uint32_t)bf16rn(p[3]) << 16) | (uint32_t)bf16rn(p[2]);
        *(uint2*)(myrow + 8u*(uint32_t)l) = make_uint2(pk0, pk1);
        grow4[l] = p;
    }
    __syncthreads();                            // (2) all P rows ready

    // ========== phase C: PV via MFMA; wave w covers m in [256w, 256w+256) ==========
    // Single accumulator (dt outer) keeps register peak low; bfrag reloaded per (dt,s).
    const ushort* Vt = wsu + VT_OFF + (size_t)h*DH*NPTS;
    const int m0 = 256*w;
    #pragma unroll
    for (int dt = 0; dt < 4; dt++) {
        f32x4 acc = {0.f, 0.f, 0.f, 0.f};
        #pragma unroll
        for (int s = 0; s < 8; s++) {
            const int mk = m0 + 32*s + 8*cg;
            bf16x8 bfrag = *(const bf16x8*)(lds + (uint32_t)qrow*8192u + 2u*(uint32_t)mk);
            bf16x8 afrag = *(const bf16x8*)(Vt + ((size_t)(16*dt + cl))*NPTS + mk);
            acc = __builtin_amdgcn_mfma_f32_16x16x32_bf16(afrag, bfrag, acc, 0, 0, 0);
        }
        // C: q-row = qrow (cl<8), d = 16dt + 4cg + reg -> partials at own wave region
        if (cl < 8) {
            uint32_t byte = (uint32_t)w*8192u + 4096u + (uint32_t)qrow*256u
                          + 64u*(uint32_t)dt + 16u*(uint32_t)cg;
            *(f32x4*)(lds + byte) = acc;
        }
    }
    __syncthreads();                            // (3) partials ready

    {   // final reduce: wave r (=w) handles row r; lane = d
        const int r = w, d = l;
        float ssum = 0.f;
        #pragma unroll
        for (int wv = 0; wv < 8; wv++)
            ssum += *(const float*)(lds + (uint32_t)wv*8192u + 4096u
                                    + (uint32_t)r*256u + 4u*(uint32_t)d);
        out[(size_t)(n0 + r)*DM + h*DH + d] = ssum;
    }
}

extern "C" void kernel_launch(void* const* d_in, const int* in_sizes, int n_in,
                              void* d_out, int out_size, void* d_ws, size_t ws_size,
                              hipStream_t stream)
{
    const float* xq  = (const float*)d_in[0];
    const float* xk  = (const float*)d_in[1];
    const float* xv  = (const float*)d_in[2];
    const float* emb = (const float*)d_in[3];
    const float* Wq  = (const float*)d_in[4];
    const float* bq  = (const float*)d_in[5];
    const float* Wk  = (const float*)d_in[6];
    const float* bk  = (const float*)d_in[7];
    const float* Wv  = (const float*)d_in[8];
    const float* bv  = (const float*)d_in[9];
    float* out  = (float*)d_out;
    ushort* wsu = (ushort*)d_ws;   // needs 5 MiB

    proj_rope_kernel<<<dim3(NPTS/8, 3), 256, 0, stream>>>(xq, xk, xv, emb, Wq, bq, Wk, bk, Wv, bv, wsu);
    fused_attn_kernel<<<dim3(NPTS/8 * NH), 512, 0, stream>>>(wsu, out);
}